// Round 5
// baseline (51.291 us; speedup 1.0000x reference)
//
#include <hip/hip_runtime.h>

// Problem shape (fixed by the reference setup)
#define TT 512
#define BB 32
#define FF 256
#define LL 8
#define NCHAIN (BB * FF * LL)   // 65536 chains
#define NGROUP (NCHAIN / 4)     // 16384 float4 groups (4 consecutive l's)

typedef float f32x4 __attribute__((ext_vector_type(4)));

// Decomposition (K1/K3): 64 blocks of 256 per chunk.
// blockLocal = blockIdx & 63; b = blockLocal>>1 (block-uniform -> resets is a
// scalar broadcast, and reset-dependent branches are wave-uniform);
// idx = ((blockLocal&1)<<8)|tid; f = idx>>1; h = idx&1; group g = (b<<9)|idx.
// Consecutive lanes -> consecutive 16B slots -> 1KiB/wave stores.

// K1: zero-init chunk scan. For t >= chunk's first reset, E_t (zero-init scan)
// is EXACT (P_t = prod a_i = 0), so write it directly. Steps before the first
// reset are left unwritten (K3 fills them). Also emits the chunk summary
// (A = prod a_t, E_end) for the prefold.
template <int NCHUNK>
__global__ __launch_bounds__(256) void k1_scan(
    const float* __restrict__ features,  // [T,B,F]
    const int*   __restrict__ resets,    // [T,B]
    const float* __restrict__ lambdas,   // [L]
    f32x4*       __restrict__ wsA,       // [NCHUNK][NGROUP]
    f32x4*       __restrict__ wsE,       // [NCHUNK][NGROUP]
    f32x4*       __restrict__ out4)      // [NGROUP] final, then [T][NGROUP]
{
    constexpr int TC = TT / NCHUNK;
    const int chunk      = blockIdx.x >> 6;
    const int blockLocal = blockIdx.x & 63;
    const int b   = blockLocal >> 1;
    const int idx = ((blockLocal & 1) << 8) | threadIdx.x;
    const int h   = idx & 1;
    const int f   = idx >> 1;
    const int g   = (b << 9) | idx;

    const f32x4 lam  = ((const f32x4*)lambdas)[h];
    const f32x4 onem = 1.0f - lam;
    const int   t0   = chunk * TC;

    const float* fptr = features + (size_t)t0 * (BB * FF) + b * FF + f;
    const int*   rptr = resets + (size_t)t0 * BB + b;
    f32x4*       yptr = out4 + NGROUP + (size_t)t0 * NGROUP + g;

    f32x4 A = 1.0f;
    f32x4 s = 0.0f;
    bool  seen = false;  // block-uniform -> wave-uniform branch
    #pragma unroll 4
    for (int t = 0; t < TC; ++t) {
        const float x = fptr[(size_t)t * (BB * FF)];
        const int   r = rptr[(size_t)t * BB];
        if (r) seen = true;
        #pragma unroll
        for (int j = 0; j < 4; ++j) {
            const float Av = A[j] * lam[j];
            const float Ev = fmaf(lam[j], s[j], onem[j] * x);
            A[j] = r ? 0.0f : Av;
            s[j] = r ? x : Ev;
        }
        if (seen) __builtin_nontemporal_store(s, yptr + (size_t)t * NGROUP);
    }
    wsA[(size_t)chunk * NGROUP + g] = A;
    wsE[(size_t)chunk * NGROUP + g] = s;
}

// K2: hierarchical prefold. One thread per chain group scans the NCHUNK
// summaries: emits each chunk's true initial state s0 and the final trace.
// Every load/store is a fully-coalesced wave access.
template <int NCHUNK>
__global__ __launch_bounds__(256) void k2_prefold(
    const float* __restrict__ carry,   // [B,F,L]
    const f32x4* __restrict__ wsA,
    const f32x4* __restrict__ wsE,
    f32x4*       __restrict__ s0ws,    // [NCHUNK][NGROUP]
    f32x4*       __restrict__ out4)
{
    const int g = blockIdx.x * 256 + threadIdx.x;  // 64 blocks

    f32x4 s = ((const f32x4*)carry)[g];
    #pragma unroll 4
    for (int cc = 0; cc < NCHUNK; ++cc) {
        const f32x4 Ac = wsA[(size_t)cc * NGROUP + g];
        const f32x4 Ec = wsE[(size_t)cc * NGROUP + g];
        s0ws[(size_t)cc * NGROUP + g] = s;
        #pragma unroll
        for (int j = 0; j < 4; ++j) s[j] = fmaf(Ac[j], s[j], Ec[j]);
    }
    out4[g] = s;  // final_trace (first output in the concatenation)
}

// K3: fill the pre-first-reset prefix of each chunk with the true scan
// starting from s0 (write-only; features are L2/L3-hot after K1).
template <int NCHUNK>
__global__ __launch_bounds__(256) void k3_fix(
    const float* __restrict__ features,
    const int*   __restrict__ resets,
    const float* __restrict__ lambdas,
    const f32x4* __restrict__ s0ws,
    f32x4*       __restrict__ out4)
{
    constexpr int TC = TT / NCHUNK;
    const int chunk      = blockIdx.x >> 6;
    const int blockLocal = blockIdx.x & 63;
    const int b   = blockLocal >> 1;
    const int idx = ((blockLocal & 1) << 8) | threadIdx.x;
    const int h   = idx & 1;
    const int f   = idx >> 1;
    const int g   = (b << 9) | idx;

    const f32x4 lam  = ((const f32x4*)lambdas)[h];
    const f32x4 onem = 1.0f - lam;
    const int   t0   = chunk * TC;

    const float* fptr = features + (size_t)t0 * (BB * FF) + b * FF + f;
    const int*   rptr = resets + (size_t)t0 * BB + b;
    f32x4*       yptr = out4 + NGROUP + (size_t)t0 * NGROUP + g;

    f32x4 s = s0ws[(size_t)chunk * NGROUP + g];
    for (int t = 0; t < TC; ++t) {
        if (rptr[(size_t)t * BB]) break;  // wave-uniform
        const float x = fptr[(size_t)t * (BB * FF)];
        #pragma unroll
        for (int j = 0; j < 4; ++j) s[j] = fmaf(lam[j], s[j], onem[j] * x);
        yptr[(size_t)t * NGROUP] = s;
    }
}

// Fallback (ws too small): round-1 single-pass kernel, known correct.
__global__ __launch_bounds__(256) void trace_rnn_fallback(
    const float* __restrict__ features,
    const int*   __restrict__ resets,
    const float* __restrict__ carry,
    const float* __restrict__ lambdas,
    float*       __restrict__ out)
{
    const int b  = blockIdx.x >> 3;
    const int fl = ((blockIdx.x & 7) << 8) | threadIdx.x;
    const int f  = fl >> 3;
    const int l  = fl & 7;
    const int gid = (b << 11) | fl;

    const float lam  = lambdas[l];
    const float onem = 1.0f - lam;

    float trace = carry[gid];
    const float* fptr = features + b * FF + f;
    const int*   rptr = resets + b;
    float*       yptr = out + NCHAIN + gid;

    #pragma unroll 4
    for (int t = 0; t < TT; ++t) {
        const float x = fptr[(size_t)t * (BB * FF)];
        const int   r = rptr[(size_t)t * BB];
        const float v = fmaf(lam, trace, onem * x);
        trace = r ? x : v;
        yptr[(size_t)t * NCHAIN] = trace;
    }
    out[gid] = trace;
}

template <int NCHUNK>
static void launch_triple(const float* features, const int* resets,
                          const float* carry, const float* lambdas,
                          void* d_ws, float* out, hipStream_t stream) {
    f32x4* wsA  = (f32x4*)d_ws;
    f32x4* wsE  = wsA + (size_t)NCHUNK * NGROUP;
    f32x4* s0ws = wsE + (size_t)NCHUNK * NGROUP;
    const int grid = NCHUNK * 64;
    k1_scan<NCHUNK><<<grid, 256, 0, stream>>>(
        features, resets, lambdas, wsA, wsE, (f32x4*)out);
    k2_prefold<NCHUNK><<<NGROUP / 256, 256, 0, stream>>>(
        carry, wsA, wsE, s0ws, (f32x4*)out);
    k3_fix<NCHUNK><<<grid, 256, 0, stream>>>(
        features, resets, lambdas, s0ws, (f32x4*)out);
}

extern "C" void kernel_launch(void* const* d_in, const int* in_sizes, int n_in,
                              void* d_out, int out_size, void* d_ws, size_t ws_size,
                              hipStream_t stream) {
    const float* features = (const float*)d_in[0];
    const int*   resets   = (const int*)d_in[1];
    const float* carry    = (const float*)d_in[2];
    const float* lambdas  = (const float*)d_in[3];
    float* out = (float*)d_out;

    // Per-NCHUNK ws need: 3 arrays x NCHUNK x NGROUP x 16B
    const size_t ws32 = (size_t)3 * 32 * NGROUP * sizeof(f32x4);  // 24 MB
    const size_t ws16 = (size_t)3 * 16 * NGROUP * sizeof(f32x4);  // 12 MB
    const size_t ws8  = (size_t)3 * 8  * NGROUP * sizeof(f32x4);  //  6 MB

    if (ws_size >= ws32) {
        launch_triple<32>(features, resets, carry, lambdas, d_ws, out, stream);
    } else if (ws_size >= ws16) {
        launch_triple<16>(features, resets, carry, lambdas, d_ws, out, stream);
    } else if (ws_size >= ws8) {
        launch_triple<8>(features, resets, carry, lambdas, d_ws, out, stream);
    } else {
        trace_rnn_fallback<<<NCHAIN / 256, 256, 0, stream>>>(
            features, resets, carry, lambdas, out);
    }
}